// Round 1
// baseline (420.847 us; speedup 1.0000x reference)
//
#include <hip/hip_runtime.h>
#include <hip/hip_bf16.h>

// Problem constants (B=8192, IN=H=1024)
#define BATCH 8192
#define HDIM  1024
#define KDIM  2048   // IN + H concatenated
#define NDIM  4096   // 4*H

__device__ inline unsigned short f2bf(float x) {
    unsigned int u = __float_as_uint(x);
    unsigned int r = (u + 0x7fffu + ((u >> 16) & 1u)) >> 16;
    return (unsigned short)r;
}

// Build Wb [4096, 2048] bf16: row n = [w_i[n] | w_h[n]], with w_i half zeroed
// for rows 2048..3071 (chunk i_gc of gi is unused by the reference; chunk 2 of
// the fused GEMM must be h_g only).
__global__ __launch_bounds__(256) void convert_w_kernel(
    const float* __restrict__ wi, const float* __restrict__ wh,
    unsigned short* __restrict__ Wb)
{
    int idx = blockIdx.x * 256 + threadIdx.x;      // 4096*512 total
    int n = idx >> 9;
    int k = (idx & 511) << 2;
    float4 v;
    if (k < 1024) {
        if (n >= 2048 && n < 3072) {
            v = make_float4(0.f, 0.f, 0.f, 0.f);
        } else {
            v = *(const float4*)(wi + (size_t)n * 1024 + k);
        }
    } else {
        v = *(const float4*)(wh + (size_t)n * 1024 + (k - 1024));
    }
    ushort4 o;
    o.x = f2bf(v.x); o.y = f2bf(v.y); o.z = f2bf(v.z); o.w = f2bf(v.w);
    *(ushort4*)(Wb + (size_t)n * KDIM + k) = o;
}

// Build Xb [8192, 2048] bf16: row r = [input[r] | h_prev[r]]
__global__ __launch_bounds__(256) void convert_x_kernel(
    const float* __restrict__ input, const float* __restrict__ h_prev,
    unsigned short* __restrict__ Xb)
{
    int idx = blockIdx.x * 256 + threadIdx.x;      // 8192*512 total
    int r = idx >> 9;
    int k = (idx & 511) << 2;
    float4 v;
    if (k < 1024) {
        v = *(const float4*)(input + (size_t)r * 1024 + k);
    } else {
        v = *(const float4*)(h_prev + (size_t)r * 1024 + (k - 1024));
    }
    ushort4 o;
    o.x = f2bf(v.x); o.y = f2bf(v.y); o.z = f2bf(v.z); o.w = f2bf(v.w);
    *(ushort4*)(Xb + (size_t)r * KDIM + k) = o;
}

// C[M,N] = A[M,K] * Bw[N,K]^T, bf16 inputs, fp32 out.
// 128x128 block tile, BK=32, 4 waves each computing 64x64 via 4x4 of
// 16x16x32 MFMAs. global_load_lds width=16 staging (m97 structure).
#define BM 128
#define BN 128
#define BK 32

typedef __attribute__((ext_vector_type(8))) short bf16x8;
typedef __attribute__((ext_vector_type(4))) float f32x4;

__global__ __launch_bounds__(256) void gemm_bt_kernel(
    const unsigned short* __restrict__ A,
    const unsigned short* __restrict__ Bw,
    float* __restrict__ C,
    int M)
{
    __shared__ unsigned short As[BM * BK];
    __shared__ unsigned short Bs[BN * BK];

    const int tid  = threadIdx.x;
    const int lane = tid & 63;
    const int wave = tid >> 6;

    const int bm = blockIdx.y * BM;
    const int bn = blockIdx.x * BN;

    f32x4 acc[4][4] = {};

    const int wm = (wave >> 1) * 64;
    const int wn = (wave & 1) * 64;

    const int srow  = lane >> 2;         // 0..15
    const int skofs = (lane & 3) * 8;    // 0,8,16,24 (bf16 elems; 16B per lane)

    for (int k0 = 0; k0 < KDIM; k0 += BK) {
#pragma unroll
        for (int p = 0; p < 2; ++p) {
            int r = wave * 32 + p * 16;
            const unsigned short* gA = A + (size_t)(bm + r + srow) * KDIM + k0 + skofs;
            unsigned short* lA = &As[r * BK];
            __builtin_amdgcn_global_load_lds(
                (const __attribute__((address_space(1))) void*)gA,
                (__attribute__((address_space(3))) void*)lA, 16, 0, 0);
            const unsigned short* gB = Bw + (size_t)(bn + r + srow) * KDIM + k0 + skofs;
            unsigned short* lB = &Bs[r * BK];
            __builtin_amdgcn_global_load_lds(
                (const __attribute__((address_space(1))) void*)gB,
                (__attribute__((address_space(3))) void*)lB, 16, 0, 0);
        }
        __syncthreads();

        bf16x8 af[4], bfr[4];
#pragma unroll
        for (int i = 0; i < 4; ++i) {
            af[i]  = *(const bf16x8*)&As[(wm + i * 16 + (lane & 15)) * BK + (lane >> 4) * 8];
            bfr[i] = *(const bf16x8*)&Bs[(wn + i * 16 + (lane & 15)) * BK + (lane >> 4) * 8];
        }
#pragma unroll
        for (int i = 0; i < 4; ++i)
#pragma unroll
            for (int j = 0; j < 4; ++j)
                acc[i][j] = __builtin_amdgcn_mfma_f32_16x16x32_bf16(af[i], bfr[j], acc[i][j], 0, 0, 0);
        __syncthreads();
    }

    // Epilogue: C/D mapping col=lane&15, row=(lane>>4)*4+reg (m89-verified)
#pragma unroll
    for (int i = 0; i < 4; ++i) {
#pragma unroll
        for (int j = 0; j < 4; ++j) {
#pragma unroll
            for (int r = 0; r < 4; ++r) {
                int row = bm + wm + i * 16 + (lane >> 4) * 4 + r;
                int col = bn + wn + j * 16 + (lane & 15);
                C[(size_t)row * NDIM + col] = acc[i][j][r];
            }
        }
    }
}

// Block-level mean/rstd over H=1024 (256 threads x 4 elems)
__device__ inline void blkstats(const float* x, float* red, int lane, int wave,
                                float& mu, float& rstd)
{
    float s = x[0] + x[1] + x[2] + x[3];
    float q = x[0] * x[0] + x[1] * x[1] + x[2] * x[2] + x[3] * x[3];
#pragma unroll
    for (int o = 32; o; o >>= 1) {
        s += __shfl_down(s, o);
        q += __shfl_down(q, o);
    }
    if (lane == 0) { red[wave] = s; red[8 + wave] = q; }
    __syncthreads();
    s = red[0] + red[1] + red[2] + red[3];
    q = red[8] + red[9] + red[10] + red[11];
    __syncthreads();
    mu = s * (1.f / 1024.f);
    float var = q * (1.f / 1024.f) - mu * mu;
    rstd = rsqrtf(var + 1e-5f);
}

__device__ inline float sigmoidf(float x) { return 1.f / (1.f + expf(-x)); }

// One block per row. G row layout: [s0=i_i+h_i | s1=i_f+h_f | s2=h_g | s3=i_o+h_o]
__global__ __launch_bounds__(256) void lstm_ew_kernel(
    const float* __restrict__ G,
    const float* __restrict__ c_prev,
    const float* __restrict__ p0g, const float* __restrict__ p0b,
    const float* __restrict__ p1g, const float* __restrict__ p1b,
    const float* __restrict__ p2g, const float* __restrict__ p2b,
    const float* __restrict__ p3g, const float* __restrict__ p3b,
    const float* __restrict__ p4g, const float* __restrict__ p4b,
    float* __restrict__ out_h, float* __restrict__ out_c,
    int row_base)
{
    const int r    = blockIdx.x;
    const int tid  = threadIdx.x;
    const int col  = tid * 4;
    const int lane = tid & 63;
    const int wave = tid >> 6;
    __shared__ float red[16];

    const float* Grow = G + (size_t)r * NDIM;
    float4 f0 = *(const float4*)&Grow[col];
    float4 f1 = *(const float4*)&Grow[1024 + col];
    float4 f2 = *(const float4*)&Grow[2048 + col];
    float4 f3 = *(const float4*)&Grow[3072 + col];
    const int grow = row_base + r;
    float4 fc = *(const float4*)&c_prev[(size_t)grow * HDIM + col];

    float v0[4] = {f0.x, f0.y, f0.z, f0.w};
    float v1[4] = {f1.x, f1.y, f1.z, f1.w};
    float v2[4] = {f2.x, f2.y, f2.z, f2.w};
    float v3[4] = {f3.x, f3.y, f3.z, f3.w};
    float cp[4] = {fc.x, fc.y, fc.z, fc.w};

    float4 g0 = *(const float4*)&p0g[col]; float4 b0 = *(const float4*)&p0b[col];
    float4 g1 = *(const float4*)&p1g[col]; float4 b1 = *(const float4*)&p1b[col];
    float4 g2 = *(const float4*)&p2g[col]; float4 b2 = *(const float4*)&p2b[col];
    float4 g3 = *(const float4*)&p3g[col]; float4 b3 = *(const float4*)&p3b[col];
    float4 g4 = *(const float4*)&p4g[col]; float4 b4 = *(const float4*)&p4b[col];
    float ga0[4] = {g0.x, g0.y, g0.z, g0.w}, bb0[4] = {b0.x, b0.y, b0.z, b0.w};
    float ga1[4] = {g1.x, g1.y, g1.z, g1.w}, bb1[4] = {b1.x, b1.y, b1.z, b1.w};
    float ga2[4] = {g2.x, g2.y, g2.z, g2.w}, bb2[4] = {b2.x, b2.y, b2.z, b2.w};
    float ga3[4] = {g3.x, g3.y, g3.z, g3.w}, bb3[4] = {b3.x, b3.y, b3.z, b3.w};
    float ga4[4] = {g4.x, g4.y, g4.z, g4.w}, bb4[4] = {b4.x, b4.y, b4.z, b4.w};

    float mu, rs;
    float ig[4], fg[4], gg[4], og[4], cm[4], cn[4], hn[4];

    // i gate: sigmoid(LN(i_i+h_i; ln_i))
    blkstats(v0, red, lane, wave, mu, rs);
#pragma unroll
    for (int j = 0; j < 4; ++j) ig[j] = sigmoidf((v0[j] - mu) * rs * ga0[j] + bb0[j]);

    // f gate: sigmoid(LN(i_f+h_f; ln_h))   <- reference uses ln_h params here
    blkstats(v1, red, lane, wave, mu, rs);
#pragma unroll
    for (int j = 0; j < 4; ++j) fg[j] = sigmoidf((v1[j] - mu) * rs * ga1[j] + bb1[j]);

    // g gate: tanh(LN(i_g + h_g; ln_g))    <- faithful bug: i_g is the sigmoided gate
    float gp[4];
#pragma unroll
    for (int j = 0; j < 4; ++j) gp[j] = ig[j] + v2[j];
    blkstats(gp, red, lane, wave, mu, rs);
#pragma unroll
    for (int j = 0; j < 4; ++j) gg[j] = tanhf((gp[j] - mu) * rs * ga2[j] + bb2[j]);

    // o gate: sigmoid(LN(i_o+h_o; ln_o))
    blkstats(v3, red, lane, wave, mu, rs);
#pragma unroll
    for (int j = 0; j < 4; ++j) og[j] = sigmoidf((v3[j] - mu) * rs * ga3[j] + bb3[j]);

    // c_new = LN(f*c_prev + i*g; ln_c)
#pragma unroll
    for (int j = 0; j < 4; ++j) cm[j] = fg[j] * cp[j] + ig[j] * gg[j];
    blkstats(cm, red, lane, wave, mu, rs);
#pragma unroll
    for (int j = 0; j < 4; ++j) {
        cn[j] = (cm[j] - mu) * rs * ga4[j] + bb4[j];
        hn[j] = og[j] * tanhf(cn[j]);
    }

    float4 oh = make_float4(hn[0], hn[1], hn[2], hn[3]);
    float4 oc = make_float4(cn[0], cn[1], cn[2], cn[3]);
    *(float4*)&out_h[(size_t)grow * HDIM + col] = oh;
    *(float4*)&out_c[(size_t)grow * HDIM + col] = oc;
}

extern "C" void kernel_launch(void* const* d_in, const int* in_sizes, int n_in,
                              void* d_out, int out_size, void* d_ws, size_t ws_size,
                              hipStream_t stream)
{
    const float* input  = (const float*)d_in[0];
    const float* h_prev = (const float*)d_in[1];
    const float* c_prev = (const float*)d_in[2];
    const float* w_i    = (const float*)d_in[3];
    const float* w_h    = (const float*)d_in[4];
    const float* lng[10];
    for (int i = 0; i < 10; ++i) lng[i] = (const float*)d_in[5 + i];

    // Workspace layout: Xb bf16 [8192,2048] | Wb bf16 [4096,2048] | G fp32 [chunk,4096]
    unsigned short* Xb = (unsigned short*)d_ws;
    size_t xb_bytes = (size_t)BATCH * KDIM * 2;
    unsigned short* Wb = (unsigned short*)((char*)d_ws + xb_bytes);
    size_t wb_bytes = (size_t)NDIM * KDIM * 2;
    float* G = (float*)((char*)d_ws + xb_bytes + wb_bytes);

    size_t g_avail = (ws_size > xb_bytes + wb_bytes) ? (ws_size - xb_bytes - wb_bytes) : 0;
    long max_rows = (long)(g_avail / ((size_t)NDIM * sizeof(float)));
    int chunk = (max_rows >= BATCH) ? BATCH : (int)((max_rows / 128) * 128);
    if (chunk <= 0) chunk = 128;   // last-resort assumption

    convert_w_kernel<<<(NDIM * 512) / 256, 256, 0, stream>>>(w_i, w_h, Wb);
    convert_x_kernel<<<(BATCH * 512) / 256, 256, 0, stream>>>(input, h_prev, Xb);

    float* out_h = (float*)d_out;
    float* out_c = out_h + (size_t)BATCH * HDIM;

    for (int rb = 0; rb < BATCH; rb += chunk) {
        int rows = (BATCH - rb < chunk) ? (BATCH - rb) : chunk;
        gemm_bt_kernel<<<dim3(NDIM / BN, rows / BM), 256, 0, stream>>>(
            Xb + (size_t)rb * KDIM, Wb, G, rows);
        lstm_ew_kernel<<<rows, 256, 0, stream>>>(
            G, c_prev, lng[0], lng[1], lng[2], lng[3], lng[4],
            lng[5], lng[6], lng[7], lng[8], lng[9], out_h, out_c, rb);
    }
}

// Round 2
// 388.177 us; speedup vs baseline: 1.0842x; 1.0842x over previous
//
#include <hip/hip_runtime.h>
#include <hip/hip_bf16.h>

// Problem constants (B=8192, IN=H=1024)
#define BATCH 8192
#define HDIM  1024
#define KDIM  2048   // IN + H concatenated
#define NDIM  4096   // 4*H

__device__ inline unsigned short f2bf(float x) {
    unsigned int u = __float_as_uint(x);
    unsigned int r = (u + 0x7fffu + ((u >> 16) & 1u)) >> 16;
    return (unsigned short)r;
}

// Build Wb [4096, 2048] bf16: row n = [w_i[n] | w_h[n]], with w_i half zeroed
// for rows 2048..3071 (chunk i_gc of gi is unused by the reference).
__global__ __launch_bounds__(256) void convert_w_kernel(
    const float* __restrict__ wi, const float* __restrict__ wh,
    unsigned short* __restrict__ Wb)
{
    int idx = blockIdx.x * 256 + threadIdx.x;      // 4096*512 total
    int n = idx >> 9;
    int k = (idx & 511) << 2;
    float4 v;
    if (k < 1024) {
        if (n >= 2048 && n < 3072) {
            v = make_float4(0.f, 0.f, 0.f, 0.f);
        } else {
            v = *(const float4*)(wi + (size_t)n * 1024 + k);
        }
    } else {
        v = *(const float4*)(wh + (size_t)n * 1024 + (k - 1024));
    }
    ushort4 o;
    o.x = f2bf(v.x); o.y = f2bf(v.y); o.z = f2bf(v.z); o.w = f2bf(v.w);
    *(ushort4*)(Wb + (size_t)n * KDIM + k) = o;
}

// Build Xb [8192, 2048] bf16: row r = [input[r] | h_prev[r]]
__global__ __launch_bounds__(256) void convert_x_kernel(
    const float* __restrict__ input, const float* __restrict__ h_prev,
    unsigned short* __restrict__ Xb)
{
    int idx = blockIdx.x * 256 + threadIdx.x;      // 8192*512 total
    int r = idx >> 9;
    int k = (idx & 511) << 2;
    float4 v;
    if (k < 1024) {
        v = *(const float4*)(input + (size_t)r * 1024 + k);
    } else {
        v = *(const float4*)(h_prev + (size_t)r * 1024 + (k - 1024));
    }
    ushort4 o;
    o.x = f2bf(v.x); o.y = f2bf(v.y); o.z = f2bf(v.z); o.w = f2bf(v.w);
    *(ushort4*)(Xb + (size_t)r * KDIM + k) = o;
}

// ---------------------------------------------------------------------------
// GEMM: C[M,N] = A[M,K] * Bw[N,K]^T, bf16 in, fp32 out.
// 128x128 tile, BK=64 (32 K-iters: half the barriers of BK=32).
// XOR-swizzled LDS k-chunks (conflict-free ds_read_b128).
// XCD-aware block remap: each XCD owns a 4-n-tile stripe (2 MB B in L2),
// with the zeroed-w_i n-stripe (k<1024 skip) round-robined for balance.
// ---------------------------------------------------------------------------
#define BM 128
#define BN 128
#define BK 64    // bf16 elems per row; 128 B

typedef __attribute__((ext_vector_type(8))) short bf16x8;
typedef __attribute__((ext_vector_type(4))) float f32x4;

__global__ __launch_bounds__(256) void gemm_bt_kernel(
    const unsigned short* __restrict__ A,
    const unsigned short* __restrict__ Bw,
    float* __restrict__ C,
    int M)
{
    __shared__ unsigned short As[BM * BK];   // 16 KB
    __shared__ unsigned short Bs[BN * BK];   // 16 KB

    const int tid  = threadIdx.x;
    const int lane = tid & 63;
    const int wave = tid >> 6;

    // swizzled block mapping: bid -> (m_tile, n_tile)
    // xcd = bid & 7 (round-robin XCD heuristic); each XCD gets n-tiles
    // {xcd, 8+xcd, 16+xcd, 24+xcd} -> 2 MB B stripe per XCD L2, and exactly
    // one half-work stripe per XCD.
    const int bid    = blockIdx.x;
    const int xcd    = bid & 7;
    const int local  = bid >> 3;
    const int n_tile = ((local & 3) << 3) + xcd;   // 0..31
    const int m_tile = local >> 2;
    const int bm = m_tile * BM;
    const int bn = n_tile * BN;

    f32x4 acc[4][4] = {};

    const int wm = (wave >> 1) * 64;
    const int wn = (wave & 1) * 64;

    // staging: lane l covers row (l>>3) of its 8-row group, LDS chunk (l&7).
    // XOR swizzle: LDS row r, position p holds global k-chunk p ^ (r&7).
    const int srow = lane >> 3;               // 0..7 (== row&7, groups are 8-aligned)
    const int c_sw = (lane & 7) ^ srow;       // global 16B-chunk to fetch

    int k0 = 0;
    if (bn >= 2048 && bn < 3072) k0 = 1024;   // w_i half of these rows is zero

    for (; k0 < KDIM; k0 += BK) {
#pragma unroll
        for (int p = 0; p < 4; ++p) {
            const int rbase = wave * 32 + p * 8;
            const unsigned short* gA =
                A + (size_t)(bm + rbase + srow) * KDIM + k0 + c_sw * 8;
            __builtin_amdgcn_global_load_lds(
                (const __attribute__((address_space(1))) void*)gA,
                (__attribute__((address_space(3))) void*)&As[rbase * BK], 16, 0, 0);
            const unsigned short* gB =
                Bw + (size_t)(bn + rbase + srow) * KDIM + k0 + c_sw * 8;
            __builtin_amdgcn_global_load_lds(
                (const __attribute__((address_space(1))) void*)gB,
                (__attribute__((address_space(3))) void*)&Bs[rbase * BK], 16, 0, 0);
        }
        __syncthreads();

#pragma unroll
        for (int kk = 0; kk < 2; ++kk) {
            bf16x8 af[4], bfr[4];
            const int cbase = kk * 4 + (lane >> 4);   // 16B-chunk index 0..7
#pragma unroll
            for (int i = 0; i < 4; ++i) {
                const int ra = wm + i * 16 + (lane & 15);
                af[i]  = *(const bf16x8*)&As[ra * BK + (cbase ^ (ra & 7)) * 8];
                const int rb = wn + i * 16 + (lane & 15);
                bfr[i] = *(const bf16x8*)&Bs[rb * BK + (cbase ^ (rb & 7)) * 8];
            }
#pragma unroll
            for (int i = 0; i < 4; ++i)
#pragma unroll
                for (int j = 0; j < 4; ++j)
                    acc[i][j] = __builtin_amdgcn_mfma_f32_16x16x32_bf16(
                        af[i], bfr[j], acc[i][j], 0, 0, 0);
        }
        __syncthreads();
    }

    // Epilogue: C/D mapping col=lane&15, row=(lane>>4)*4+reg (m89-verified)
#pragma unroll
    for (int i = 0; i < 4; ++i) {
#pragma unroll
        for (int j = 0; j < 4; ++j) {
#pragma unroll
            for (int r = 0; r < 4; ++r) {
                int row = bm + wm + i * 16 + (lane >> 4) * 4 + r;
                int col = bn + wn + j * 16 + (lane & 15);
                C[(size_t)row * NDIM + col] = acc[i][j][r];
            }
        }
    }
}

// ---------------------------------------------------------------------------
// Elementwise: wave-per-row, pure shuffle reductions, no barriers / LDS.
// G row layout: [s0=i_i+h_i | s1=i_f+h_f | s2=h_g | s3=i_o+h_o]
// ---------------------------------------------------------------------------
__device__ inline float sigmoid_f(float x) { return 1.f / (1.f + __expf(-x)); }
// safe fast tanh: exact +/-1 saturation at both ends
__device__ inline float tanh_f(float x) { return 1.f - 2.f / (__expf(2.f * x) + 1.f); }

__device__ inline void wstats(const float* x, float& mu, float& rs)
{
    float s = 0.f, q = 0.f;
#pragma unroll
    for (int e = 0; e < 16; ++e) { s += x[e]; q += x[e] * x[e]; }
#pragma unroll
    for (int o = 1; o < 64; o <<= 1) {
        s += __shfl_xor(s, o);
        q += __shfl_xor(q, o);
    }
    mu = s * (1.f / 1024.f);
    float var = q * (1.f / 1024.f) - mu * mu;
    rs = rsqrtf(var + 1e-5f);
}

#define LOAD16(dst, base)                                              \
    _Pragma("unroll")                                                  \
    for (int j = 0; j < 4; ++j) {                                      \
        float4 t = *(const float4*)((base) + j * 256 + cbase);         \
        dst[4 * j] = t.x; dst[4 * j + 1] = t.y;                        \
        dst[4 * j + 2] = t.z; dst[4 * j + 3] = t.w;                    \
    }

__global__ __launch_bounds__(256) void lstm_ew_kernel(
    const float* __restrict__ G,
    const float* __restrict__ c_prev,
    const float* __restrict__ p0g, const float* __restrict__ p0b,
    const float* __restrict__ p1g, const float* __restrict__ p1b,
    const float* __restrict__ p2g, const float* __restrict__ p2b,
    const float* __restrict__ p3g, const float* __restrict__ p3b,
    const float* __restrict__ p4g, const float* __restrict__ p4b,
    float* __restrict__ out_h, float* __restrict__ out_c,
    int row_base)
{
    const int lane  = threadIdx.x & 63;
    const int wave  = threadIdx.x >> 6;
    const int r     = blockIdx.x * 4 + wave;
    const int grow  = row_base + r;
    const int cbase = lane * 4;

    const float* Grow = G + (size_t)r * NDIM;

    float tmp[16], pg[16], pb[16];
    float ig[16], cm[16], og[16];
    float mu, rs;

    // i gate: sigmoid(LN(i_i+h_i; ln_i))
    LOAD16(tmp, Grow);
    wstats(tmp, mu, rs);
    LOAD16(pg, p0g); LOAD16(pb, p0b);
#pragma unroll
    for (int e = 0; e < 16; ++e)
        ig[e] = sigmoid_f((tmp[e] - mu) * rs * pg[e] + pb[e]);

    // f gate: sigmoid(LN(i_f+h_f; ln_h)); cm = f * c_prev
    LOAD16(tmp, Grow + 1024);
    wstats(tmp, mu, rs);
    LOAD16(pg, p1g); LOAD16(pb, p1b);
    LOAD16(cm, c_prev + (size_t)grow * HDIM);
#pragma unroll
    for (int e = 0; e < 16; ++e)
        cm[e] *= sigmoid_f((tmp[e] - mu) * rs * pg[e] + pb[e]);

    // g gate: tanh(LN(i_g + h_g; ln_g))  <- faithful bug: i_g is sigmoided gate
    LOAD16(tmp, Grow + 2048);
#pragma unroll
    for (int e = 0; e < 16; ++e) tmp[e] += ig[e];
    wstats(tmp, mu, rs);
    LOAD16(pg, p2g); LOAD16(pb, p2b);
#pragma unroll
    for (int e = 0; e < 16; ++e)
        cm[e] += ig[e] * tanh_f((tmp[e] - mu) * rs * pg[e] + pb[e]);

    // o gate: sigmoid(LN(i_o+h_o; ln_o))
    LOAD16(tmp, Grow + 3072);
    wstats(tmp, mu, rs);
    LOAD16(pg, p3g); LOAD16(pb, p3b);
#pragma unroll
    for (int e = 0; e < 16; ++e)
        og[e] = sigmoid_f((tmp[e] - mu) * rs * pg[e] + pb[e]);

    // c_new = LN(cm; ln_c); h_new = o * tanh(c_new)
    wstats(cm, mu, rs);
    LOAD16(pg, p4g); LOAD16(pb, p4b);
    float cn[16], hn[16];
#pragma unroll
    for (int e = 0; e < 16; ++e) {
        cn[e] = (cm[e] - mu) * rs * pg[e] + pb[e];
        hn[e] = og[e] * tanh_f(cn[e]);
    }

    float* oh = out_h + (size_t)grow * HDIM;
    float* oc = out_c + (size_t)grow * HDIM;
#pragma unroll
    for (int j = 0; j < 4; ++j) {
        *(float4*)(oh + j * 256 + cbase) =
            make_float4(hn[4 * j], hn[4 * j + 1], hn[4 * j + 2], hn[4 * j + 3]);
        *(float4*)(oc + j * 256 + cbase) =
            make_float4(cn[4 * j], cn[4 * j + 1], cn[4 * j + 2], cn[4 * j + 3]);
    }
}

extern "C" void kernel_launch(void* const* d_in, const int* in_sizes, int n_in,
                              void* d_out, int out_size, void* d_ws, size_t ws_size,
                              hipStream_t stream)
{
    const float* input  = (const float*)d_in[0];
    const float* h_prev = (const float*)d_in[1];
    const float* c_prev = (const float*)d_in[2];
    const float* w_i    = (const float*)d_in[3];
    const float* w_h    = (const float*)d_in[4];
    const float* lng[10];
    for (int i = 0; i < 10; ++i) lng[i] = (const float*)d_in[5 + i];

    // Workspace: Xb bf16 [8192,2048] | Wb bf16 [4096,2048] | G fp32 [chunk,4096]
    unsigned short* Xb = (unsigned short*)d_ws;
    size_t xb_bytes = (size_t)BATCH * KDIM * 2;
    unsigned short* Wb = (unsigned short*)((char*)d_ws + xb_bytes);
    size_t wb_bytes = (size_t)NDIM * KDIM * 2;
    float* G = (float*)((char*)d_ws + xb_bytes + wb_bytes);

    size_t g_avail = (ws_size > xb_bytes + wb_bytes) ? (ws_size - xb_bytes - wb_bytes) : 0;
    long max_rows = (long)(g_avail / ((size_t)NDIM * sizeof(float)));
    int chunk = (max_rows >= BATCH) ? BATCH : (int)((max_rows / 128) * 128);
    if (chunk <= 0) chunk = 128;   // last-resort assumption

    convert_w_kernel<<<(NDIM * 512) / 256, 256, 0, stream>>>(w_i, w_h, Wb);
    convert_x_kernel<<<(BATCH * 512) / 256, 256, 0, stream>>>(input, h_prev, Xb);

    float* out_h = (float*)d_out;
    float* out_c = out_h + (size_t)BATCH * HDIM;

    for (int rb = 0; rb < BATCH; rb += chunk) {
        int rows = (BATCH - rb < chunk) ? (BATCH - rb) : chunk;
        gemm_bt_kernel<<<(rows / BM) * (NDIM / BN), 256, 0, stream>>>(
            Xb + (size_t)rb * KDIM, Wb, G, rows);
        lstm_ew_kernel<<<rows / 4, 256, 0, stream>>>(
            G, c_prev, lng[0], lng[1], lng[2], lng[3], lng[4],
            lng[5], lng[6], lng[7], lng[8], lng[9], out_h, out_c, rb);
    }
}

// Round 3
// 352.962 us; speedup vs baseline: 1.1923x; 1.0998x over previous
//
#include <hip/hip_runtime.h>
#include <hip/hip_bf16.h>

// Problem constants (B=8192, IN=H=1024)
#define BATCH 8192
#define HDIM  1024
#define KDIM  2048   // IN + H concatenated
#define NDIM  4096   // 4*H

__device__ inline unsigned short f2bf(float x) {
    unsigned int u = __float_as_uint(x);
    unsigned int r = (u + 0x7fffu + ((u >> 16) & 1u)) >> 16;
    return (unsigned short)r;
}

// Build Wb [4096, 2048] bf16: row n = [w_i[n] | w_h[n]], with w_i half zeroed
// for rows 2048..3071 (chunk i_gc of gi is unused by the reference).
__global__ __launch_bounds__(256) void convert_w_kernel(
    const float* __restrict__ wi, const float* __restrict__ wh,
    unsigned short* __restrict__ Wb)
{
    int idx = blockIdx.x * 256 + threadIdx.x;      // 4096*512 total
    int n = idx >> 9;
    int k = (idx & 511) << 2;
    float4 v;
    if (k < 1024) {
        if (n >= 2048 && n < 3072) {
            v = make_float4(0.f, 0.f, 0.f, 0.f);
        } else {
            v = *(const float4*)(wi + (size_t)n * 1024 + k);
        }
    } else {
        v = *(const float4*)(wh + (size_t)n * 1024 + (k - 1024));
    }
    ushort4 o;
    o.x = f2bf(v.x); o.y = f2bf(v.y); o.z = f2bf(v.z); o.w = f2bf(v.w);
    *(ushort4*)(Wb + (size_t)n * KDIM + k) = o;
}

// Build Xb [8192, 2048] bf16: row r = [input[r] | h_prev[r]]
__global__ __launch_bounds__(256) void convert_x_kernel(
    const float* __restrict__ input, const float* __restrict__ h_prev,
    unsigned short* __restrict__ Xb)
{
    int idx = blockIdx.x * 256 + threadIdx.x;      // 8192*512 total
    int r = idx >> 9;
    int k = (idx & 511) << 2;
    float4 v;
    if (k < 1024) {
        v = *(const float4*)(input + (size_t)r * 1024 + k);
    } else {
        v = *(const float4*)(h_prev + (size_t)r * 1024 + (k - 1024));
    }
    ushort4 o;
    o.x = f2bf(v.x); o.y = f2bf(v.y); o.z = f2bf(v.z); o.w = f2bf(v.w);
    *(ushort4*)(Xb + (size_t)r * KDIM + k) = o;
}

// ---------------------------------------------------------------------------
// GEMM: C[M,N] = A[M,K] * Bw[N,K]^T, bf16 in, fp32 out.
// 256x128 tile, 512 threads (8 waves, 4m x 2n of 64x64 wave-tiles), BK=64.
// Rationale (R2 post-mortem): barrier-drain events and L2 staging traffic
// both scale with block count; 256x128 halves block-iters vs 128x128 while
// keeping per-wave register footprint identical (~90 VGPR).
// XOR-swizzled LDS k-chunks -> 0 bank conflicts (verified R2).
// Linear n-fastest block order (R2's XCD remap RAISED fetch 164->226 MB).
// ---------------------------------------------------------------------------
#define BM 256
#define BN 128
#define BK 64    // bf16 elems per row; 128 B

typedef __attribute__((ext_vector_type(8))) short bf16x8;
typedef __attribute__((ext_vector_type(4))) float f32x4;

__global__ __launch_bounds__(512) void gemm_bt_kernel(
    const unsigned short* __restrict__ A,
    const unsigned short* __restrict__ Bw,
    float* __restrict__ C,
    int M)
{
    __shared__ unsigned short As[BM * BK];   // 32 KB
    __shared__ unsigned short Bs[BN * BK];   // 16 KB

    const int tid  = threadIdx.x;
    const int lane = tid & 63;
    const int wave = tid >> 6;               // 0..7

    const int bid = blockIdx.x;              // n-fastest linear
    const int bm  = (bid >> 5) * BM;
    const int bn  = (bid & 31) * BN;

    f32x4 acc[4][4] = {};

    const int wm = (wave >> 1) * 64;         // 0,64,128,192
    const int wn = (wave & 1) * 64;          // 0,64

    // staging: lane l covers row (l>>3) of its 8-row group, LDS chunk (l&7).
    // XOR swizzle: LDS row r, position p holds global k-chunk p ^ (r&7).
    const int srow = lane >> 3;              // 0..7
    const int c_sw = (lane & 7) ^ srow;      // global 16B-chunk to fetch

    int k0 = 0;
    if (bn >= 2048 && bn < 3072) k0 = 1024;  // w_i half of these rows is zero

    for (; k0 < KDIM; k0 += BK) {
        // A: 4 loads/wave covering rows [wave*32, wave*32+32)
#pragma unroll
        for (int p = 0; p < 4; ++p) {
            const int rbase = wave * 32 + p * 8;
            const unsigned short* gA =
                A + (size_t)(bm + rbase + srow) * KDIM + k0 + c_sw * 8;
            __builtin_amdgcn_global_load_lds(
                (const __attribute__((address_space(1))) void*)gA,
                (__attribute__((address_space(3))) void*)&As[rbase * BK], 16, 0, 0);
        }
        // B: 2 loads/wave covering rows [wave*16, wave*16+16)
#pragma unroll
        for (int p = 0; p < 2; ++p) {
            const int rbase = wave * 16 + p * 8;
            const unsigned short* gB =
                Bw + (size_t)(bn + rbase + srow) * KDIM + k0 + c_sw * 8;
            __builtin_amdgcn_global_load_lds(
                (const __attribute__((address_space(1))) void*)gB,
                (__attribute__((address_space(3))) void*)&Bs[rbase * BK], 16, 0, 0);
        }
        __syncthreads();

#pragma unroll
        for (int kk = 0; kk < 2; ++kk) {
            bf16x8 af[4], bfr[4];
            const int cbase = kk * 4 + (lane >> 4);   // 16B-chunk index 0..7
#pragma unroll
            for (int i = 0; i < 4; ++i) {
                const int ra = wm + i * 16 + (lane & 15);
                af[i]  = *(const bf16x8*)&As[ra * BK + ((cbase ^ (ra & 7)) * 8)];
                const int rb = wn + i * 16 + (lane & 15);
                bfr[i] = *(const bf16x8*)&Bs[rb * BK + ((cbase ^ (rb & 7)) * 8)];
            }
#pragma unroll
            for (int i = 0; i < 4; ++i)
#pragma unroll
                for (int j = 0; j < 4; ++j)
                    acc[i][j] = __builtin_amdgcn_mfma_f32_16x16x32_bf16(
                        af[i], bfr[j], acc[i][j], 0, 0, 0);
        }
        __syncthreads();
    }

    // Epilogue: C/D mapping col=lane&15, row=(lane>>4)*4+reg (m89-verified)
#pragma unroll
    for (int i = 0; i < 4; ++i) {
#pragma unroll
        for (int j = 0; j < 4; ++j) {
#pragma unroll
            for (int r = 0; r < 4; ++r) {
                int row = bm + wm + i * 16 + (lane >> 4) * 4 + r;
                int col = bn + wn + j * 16 + (lane & 15);
                C[(size_t)row * NDIM + col] = acc[i][j][r];
            }
        }
    }
}

// ---------------------------------------------------------------------------
// Elementwise: wave-per-row, pure shuffle reductions, no barriers / LDS.
// G row layout: [s0=i_i+h_i | s1=i_f+h_f | s2=h_g | s3=i_o+h_o]
// ---------------------------------------------------------------------------
__device__ inline float sigmoid_f(float x) { return 1.f / (1.f + __expf(-x)); }
// safe fast tanh: exact +/-1 saturation at both ends
__device__ inline float tanh_f(float x) { return 1.f - 2.f / (__expf(2.f * x) + 1.f); }

__device__ inline void wstats(const float* x, float& mu, float& rs)
{
    float s = 0.f, q = 0.f;
#pragma unroll
    for (int e = 0; e < 16; ++e) { s += x[e]; q += x[e] * x[e]; }
#pragma unroll
    for (int o = 1; o < 64; o <<= 1) {
        s += __shfl_xor(s, o);
        q += __shfl_xor(q, o);
    }
    mu = s * (1.f / 1024.f);
    float var = q * (1.f / 1024.f) - mu * mu;
    rs = rsqrtf(var + 1e-5f);
}

#define LOAD16(dst, base)                                              \
    _Pragma("unroll")                                                  \
    for (int j = 0; j < 4; ++j) {                                      \
        float4 t = *(const float4*)((base) + j * 256 + cbase);         \
        dst[4 * j] = t.x; dst[4 * j + 1] = t.y;                        \
        dst[4 * j + 2] = t.z; dst[4 * j + 3] = t.w;                    \
    }

__global__ __launch_bounds__(256) void lstm_ew_kernel(
    const float* __restrict__ G,
    const float* __restrict__ c_prev,
    const float* __restrict__ p0g, const float* __restrict__ p0b,
    const float* __restrict__ p1g, const float* __restrict__ p1b,
    const float* __restrict__ p2g, const float* __restrict__ p2b,
    const float* __restrict__ p3g, const float* __restrict__ p3b,
    const float* __restrict__ p4g, const float* __restrict__ p4b,
    float* __restrict__ out_h, float* __restrict__ out_c,
    int row_base)
{
    const int lane  = threadIdx.x & 63;
    const int wave  = threadIdx.x >> 6;
    const int r     = blockIdx.x * 4 + wave;
    const int grow  = row_base + r;
    const int cbase = lane * 4;

    const float* Grow = G + (size_t)r * NDIM;

    float tmp[16], pg[16], pb[16];
    float ig[16], cm[16], og[16];
    float mu, rs;

    // i gate: sigmoid(LN(i_i+h_i; ln_i))
    LOAD16(tmp, Grow);
    wstats(tmp, mu, rs);
    LOAD16(pg, p0g); LOAD16(pb, p0b);
#pragma unroll
    for (int e = 0; e < 16; ++e)
        ig[e] = sigmoid_f((tmp[e] - mu) * rs * pg[e] + pb[e]);

    // f gate: sigmoid(LN(i_f+h_f; ln_h)); cm = f * c_prev
    LOAD16(tmp, Grow + 1024);
    wstats(tmp, mu, rs);
    LOAD16(pg, p1g); LOAD16(pb, p1b);
    LOAD16(cm, c_prev + (size_t)grow * HDIM);
#pragma unroll
    for (int e = 0; e < 16; ++e)
        cm[e] *= sigmoid_f((tmp[e] - mu) * rs * pg[e] + pb[e]);

    // g gate: tanh(LN(i_g + h_g; ln_g))  <- faithful bug: i_g is sigmoided gate
    LOAD16(tmp, Grow + 2048);
#pragma unroll
    for (int e = 0; e < 16; ++e) tmp[e] += ig[e];
    wstats(tmp, mu, rs);
    LOAD16(pg, p2g); LOAD16(pb, p2b);
#pragma unroll
    for (int e = 0; e < 16; ++e)
        cm[e] += ig[e] * tanh_f((tmp[e] - mu) * rs * pg[e] + pb[e]);

    // o gate: sigmoid(LN(i_o+h_o; ln_o))
    LOAD16(tmp, Grow + 3072);
    wstats(tmp, mu, rs);
    LOAD16(pg, p3g); LOAD16(pb, p3b);
#pragma unroll
    for (int e = 0; e < 16; ++e)
        og[e] = sigmoid_f((tmp[e] - mu) * rs * pg[e] + pb[e]);

    // c_new = LN(cm; ln_c); h_new = o * tanh(c_new)
    wstats(cm, mu, rs);
    LOAD16(pg, p4g); LOAD16(pb, p4b);
    float cn[16], hn[16];
#pragma unroll
    for (int e = 0; e < 16; ++e) {
        cn[e] = (cm[e] - mu) * rs * pg[e] + pb[e];
        hn[e] = og[e] * tanh_f(cn[e]);
    }

    float* oh = out_h + (size_t)grow * HDIM;
    float* oc = out_c + (size_t)grow * HDIM;
#pragma unroll
    for (int j = 0; j < 4; ++j) {
        *(float4*)(oh + j * 256 + cbase) =
            make_float4(hn[4 * j], hn[4 * j + 1], hn[4 * j + 2], hn[4 * j + 3]);
        *(float4*)(oc + j * 256 + cbase) =
            make_float4(cn[4 * j], cn[4 * j + 1], cn[4 * j + 2], cn[4 * j + 3]);
    }
}

extern "C" void kernel_launch(void* const* d_in, const int* in_sizes, int n_in,
                              void* d_out, int out_size, void* d_ws, size_t ws_size,
                              hipStream_t stream)
{
    const float* input  = (const float*)d_in[0];
    const float* h_prev = (const float*)d_in[1];
    const float* c_prev = (const float*)d_in[2];
    const float* w_i    = (const float*)d_in[3];
    const float* w_h    = (const float*)d_in[4];
    const float* lng[10];
    for (int i = 0; i < 10; ++i) lng[i] = (const float*)d_in[5 + i];

    // Workspace: Xb bf16 [8192,2048] | Wb bf16 [4096,2048] | G fp32 [chunk,4096]
    unsigned short* Xb = (unsigned short*)d_ws;
    size_t xb_bytes = (size_t)BATCH * KDIM * 2;
    unsigned short* Wb = (unsigned short*)((char*)d_ws + xb_bytes);
    size_t wb_bytes = (size_t)NDIM * KDIM * 2;
    float* G = (float*)((char*)d_ws + xb_bytes + wb_bytes);

    size_t g_avail = (ws_size > xb_bytes + wb_bytes) ? (ws_size - xb_bytes - wb_bytes) : 0;
    long max_rows = (long)(g_avail / ((size_t)NDIM * sizeof(float)));
    int chunk = (max_rows >= BATCH) ? BATCH : (int)((max_rows / BM) * BM);
    if (chunk <= 0) chunk = BM;   // last-resort assumption

    convert_w_kernel<<<(NDIM * 512) / 256, 256, 0, stream>>>(w_i, w_h, Wb);
    convert_x_kernel<<<(BATCH * 512) / 256, 256, 0, stream>>>(input, h_prev, Xb);

    float* out_h = (float*)d_out;
    float* out_c = out_h + (size_t)BATCH * HDIM;

    for (int rb = 0; rb < BATCH; rb += chunk) {
        int rows = (BATCH - rb < chunk) ? (BATCH - rb) : chunk;
        gemm_bt_kernel<<<(rows / BM) * (NDIM / BN), 512, 0, stream>>>(
            Xb + (size_t)rb * KDIM, Wb, G, rows);
        lstm_ew_kernel<<<rows / 4, 256, 0, stream>>>(
            G, c_prev, lng[0], lng[1], lng[2], lng[3], lng[4],
            lng[5], lng[6], lng[7], lng[8], lng[9], out_h, out_c, rb);
    }
}

// Round 4
// 335.074 us; speedup vs baseline: 1.2560x; 1.0534x over previous
//
#include <hip/hip_runtime.h>
#include <hip/hip_bf16.h>

// Problem constants (B=8192, IN=H=1024)
#define BATCH 8192
#define HDIM  1024
#define KDIM  2048   // IN + H concatenated
#define NDIM  4096   // 4*H

__device__ inline unsigned short f2bf(float x) {
    unsigned int u = __float_as_uint(x);
    unsigned int r = (u + 0x7fffu + ((u >> 16) & 1u)) >> 16;
    return (unsigned short)r;
}
__device__ inline float bf2f(unsigned short u) {
    return __uint_as_float((unsigned int)u << 16);
}

// Merged converter:
//  Wb [4096,2048] bf16: row n = [w_i[n] | w_h[n]], w_i half zeroed for rows
//  2048..3071 (chunk i_gc of gi is unused by the reference).
//  Xb [8192,2048] bf16: row r = [input[r] | h_prev[r]]
__global__ __launch_bounds__(256) void convert_kernel(
    const float* __restrict__ wi, const float* __restrict__ wh,
    const float* __restrict__ input, const float* __restrict__ h_prev,
    unsigned short* __restrict__ Wb, unsigned short* __restrict__ Xb)
{
    int idx = blockIdx.x * 256 + threadIdx.x;
    const int NW = NDIM * 512;              // weight-element groups
    float4 v;
    unsigned short* dst;
    if (idx < NW) {
        int n = idx >> 9;
        int k = (idx & 511) << 2;
        if (k < 1024) {
            if (n >= 2048 && n < 3072) v = make_float4(0.f, 0.f, 0.f, 0.f);
            else                       v = *(const float4*)(wi + (size_t)n * 1024 + k);
        } else {
            v = *(const float4*)(wh + (size_t)n * 1024 + (k - 1024));
        }
        dst = Wb + (size_t)n * KDIM + k;
    } else {
        int j = idx - NW;
        int r = j >> 9;
        int k = (j & 511) << 2;
        if (k < 1024) v = *(const float4*)(input  + (size_t)r * 1024 + k);
        else          v = *(const float4*)(h_prev + (size_t)r * 1024 + (k - 1024));
        dst = Xb + (size_t)r * KDIM + k;
    }
    ushort4 o;
    o.x = f2bf(v.x); o.y = f2bf(v.y); o.z = f2bf(v.z); o.w = f2bf(v.w);
    *(ushort4*)dst = o;
}

// ---------------------------------------------------------------------------
// GEMM: G[M,N](bf16) = A[M,K](bf16) * Bw[N,K](bf16)^T
// 256x128 tile, 512 threads (8 waves, 4m x 2n of 64x64 wave-tiles), BK=64.
// XOR-swizzled LDS k-chunks -> 0 bank conflicts (verified R2/R3).
// Linear n-fastest block order (R2's XCD remap raised fetch; reverted R3).
// R4: G stored as bf16 (halves write traffic; ew read traffic halves too).
// ---------------------------------------------------------------------------
#define BM 256
#define BN 128
#define BK 64    // bf16 elems per row; 128 B

typedef __attribute__((ext_vector_type(8))) short bf16x8;
typedef __attribute__((ext_vector_type(4))) float f32x4;

__global__ __launch_bounds__(512) void gemm_bt_kernel(
    const unsigned short* __restrict__ A,
    const unsigned short* __restrict__ Bw,
    unsigned short* __restrict__ G,
    int M)
{
    __shared__ unsigned short As[BM * BK];   // 32 KB
    __shared__ unsigned short Bs[BN * BK];   // 16 KB

    const int tid  = threadIdx.x;
    const int lane = tid & 63;
    const int wave = tid >> 6;               // 0..7

    const int bid = blockIdx.x;              // n-fastest linear
    const int bm  = (bid >> 5) * BM;
    const int bn  = (bid & 31) * BN;

    f32x4 acc[4][4] = {};

    const int wm = (wave >> 1) * 64;         // 0,64,128,192
    const int wn = (wave & 1) * 64;          // 0,64

    // staging: lane l covers row (l>>3) of its 8-row group, LDS chunk (l&7).
    // XOR swizzle: LDS row r, position p holds global k-chunk p ^ (r&7).
    const int srow = lane >> 3;              // 0..7
    const int c_sw = (lane & 7) ^ srow;      // global 16B-chunk to fetch

    int k0 = 0;
    if (bn >= 2048 && bn < 3072) k0 = 1024;  // w_i half of these rows is zero

    for (; k0 < KDIM; k0 += BK) {
        // A: 4 loads/wave covering rows [wave*32, wave*32+32)
#pragma unroll
        for (int p = 0; p < 4; ++p) {
            const int rbase = wave * 32 + p * 8;
            const unsigned short* gA =
                A + (size_t)(bm + rbase + srow) * KDIM + k0 + c_sw * 8;
            __builtin_amdgcn_global_load_lds(
                (const __attribute__((address_space(1))) void*)gA,
                (__attribute__((address_space(3))) void*)&As[rbase * BK], 16, 0, 0);
        }
        // B: 2 loads/wave covering rows [wave*16, wave*16+16)
#pragma unroll
        for (int p = 0; p < 2; ++p) {
            const int rbase = wave * 16 + p * 8;
            const unsigned short* gB =
                Bw + (size_t)(bn + rbase + srow) * KDIM + k0 + c_sw * 8;
            __builtin_amdgcn_global_load_lds(
                (const __attribute__((address_space(1))) void*)gB,
                (__attribute__((address_space(3))) void*)&Bs[rbase * BK], 16, 0, 0);
        }
        __syncthreads();

#pragma unroll
        for (int kk = 0; kk < 2; ++kk) {
            bf16x8 af[4], bfr[4];
            const int cbase = kk * 4 + (lane >> 4);   // 16B-chunk index 0..7
#pragma unroll
            for (int i = 0; i < 4; ++i) {
                const int ra = wm + i * 16 + (lane & 15);
                af[i]  = *(const bf16x8*)&As[ra * BK + ((cbase ^ (ra & 7)) * 8)];
                const int rb = wn + i * 16 + (lane & 15);
                bfr[i] = *(const bf16x8*)&Bs[rb * BK + ((cbase ^ (rb & 7)) * 8)];
            }
#pragma unroll
            for (int i = 0; i < 4; ++i)
#pragma unroll
                for (int j = 0; j < 4; ++j)
                    acc[i][j] = __builtin_amdgcn_mfma_f32_16x16x32_bf16(
                        af[i], bfr[j], acc[i][j], 0, 0, 0);
        }
        __syncthreads();
    }

    // Epilogue: C/D mapping col=lane&15, row=(lane>>4)*4+reg (m89-verified).
    // bf16 stores (2B): halves G write traffic.
#pragma unroll
    for (int i = 0; i < 4; ++i) {
#pragma unroll
        for (int j = 0; j < 4; ++j) {
#pragma unroll
            for (int r = 0; r < 4; ++r) {
                int row = bm + wm + i * 16 + (lane >> 4) * 4 + r;
                int col = bn + wn + j * 16 + (lane & 15);
                G[(size_t)row * NDIM + col] = f2bf(acc[i][j][r]);
            }
        }
    }
}

// ---------------------------------------------------------------------------
// Elementwise: wave-per-row, pure shuffle reductions, no barriers / LDS.
// G (bf16) row layout: [s0=i_i+h_i | s1=i_f+h_f | s2=h_g | s3=i_o+h_o]
// Lane l covers cols {j*512 + l*8 + e : j in 0..1, e in 0..7}.
// ---------------------------------------------------------------------------
__device__ inline float sigmoid_f(float x) { return 1.f / (1.f + __expf(-x)); }
// safe fast tanh: exact +/-1 saturation at both ends
__device__ inline float tanh_f(float x) { return 1.f - 2.f / (__expf(2.f * x) + 1.f); }

typedef __attribute__((ext_vector_type(8))) unsigned short us8;

__device__ inline void wstats(const float* x, float& mu, float& rs)
{
    float s = 0.f, q = 0.f;
#pragma unroll
    for (int e = 0; e < 16; ++e) { s += x[e]; q += x[e] * x[e]; }
#pragma unroll
    for (int o = 1; o < 64; o <<= 1) {
        s += __shfl_xor(s, o);
        q += __shfl_xor(q, o);
    }
    mu = s * (1.f / 1024.f);
    float var = q * (1.f / 1024.f) - mu * mu;
    rs = rsqrtf(var + 1e-5f);
}

// 16 bf16 -> fp32 per thread: two 16B ushort8 loads
#define LOADG16(dst, basep)                                            \
    _Pragma("unroll")                                                  \
    for (int j = 0; j < 2; ++j) {                                      \
        us8 t = *(const us8*)((basep) + j * 512 + cbase);              \
        _Pragma("unroll")                                              \
        for (int e = 0; e < 8; ++e) dst[j * 8 + e] = bf2f(t[e]);       \
    }

// 16 fp32 per thread (params / c_prev): four float4 loads
#define LOADF16(dst, basep)                                            \
    _Pragma("unroll")                                                  \
    for (int j = 0; j < 2; ++j) {                                      \
        float4 a = *(const float4*)((basep) + j * 512 + cbase);        \
        float4 b = *(const float4*)((basep) + j * 512 + cbase + 4);    \
        dst[j * 8 + 0] = a.x; dst[j * 8 + 1] = a.y;                    \
        dst[j * 8 + 2] = a.z; dst[j * 8 + 3] = a.w;                    \
        dst[j * 8 + 4] = b.x; dst[j * 8 + 5] = b.y;                    \
        dst[j * 8 + 6] = b.z; dst[j * 8 + 7] = b.w;                    \
    }

__global__ __launch_bounds__(256) void lstm_ew_kernel(
    const unsigned short* __restrict__ G,
    const float* __restrict__ c_prev,
    const float* __restrict__ p0g, const float* __restrict__ p0b,
    const float* __restrict__ p1g, const float* __restrict__ p1b,
    const float* __restrict__ p2g, const float* __restrict__ p2b,
    const float* __restrict__ p3g, const float* __restrict__ p3b,
    const float* __restrict__ p4g, const float* __restrict__ p4b,
    float* __restrict__ out_h, float* __restrict__ out_c,
    int row_base)
{
    const int lane  = threadIdx.x & 63;
    const int wave  = threadIdx.x >> 6;
    const int r     = blockIdx.x * 4 + wave;
    const int grow  = row_base + r;
    const int cbase = lane * 8;

    const unsigned short* Grow = G + (size_t)r * NDIM;

    float tmp[16], pg[16], pb[16];
    float ig[16], cm[16], og[16];
    float mu, rs;

    // i gate: sigmoid(LN(i_i+h_i; ln_i))
    LOADG16(tmp, Grow);
    wstats(tmp, mu, rs);
    LOADF16(pg, p0g); LOADF16(pb, p0b);
#pragma unroll
    for (int e = 0; e < 16; ++e)
        ig[e] = sigmoid_f((tmp[e] - mu) * rs * pg[e] + pb[e]);

    // f gate: sigmoid(LN(i_f+h_f; ln_h)); cm = f * c_prev
    LOADG16(tmp, Grow + 1024);
    wstats(tmp, mu, rs);
    LOADF16(pg, p1g); LOADF16(pb, p1b);
    LOADF16(cm, c_prev + (size_t)grow * HDIM);
#pragma unroll
    for (int e = 0; e < 16; ++e)
        cm[e] *= sigmoid_f((tmp[e] - mu) * rs * pg[e] + pb[e]);

    // g gate: tanh(LN(i_g + h_g; ln_g))  <- faithful bug: i_g is sigmoided gate
    LOADG16(tmp, Grow + 2048);
#pragma unroll
    for (int e = 0; e < 16; ++e) tmp[e] += ig[e];
    wstats(tmp, mu, rs);
    LOADF16(pg, p2g); LOADF16(pb, p2b);
#pragma unroll
    for (int e = 0; e < 16; ++e)
        cm[e] += ig[e] * tanh_f((tmp[e] - mu) * rs * pg[e] + pb[e]);

    // o gate: sigmoid(LN(i_o+h_o; ln_o))
    LOADG16(tmp, Grow + 3072);
    wstats(tmp, mu, rs);
    LOADF16(pg, p3g); LOADF16(pb, p3b);
#pragma unroll
    for (int e = 0; e < 16; ++e)
        og[e] = sigmoid_f((tmp[e] - mu) * rs * pg[e] + pb[e]);

    // c_new = LN(cm; ln_c); h_new = o * tanh(c_new)
    wstats(cm, mu, rs);
    LOADF16(pg, p4g); LOADF16(pb, p4b);
    float cn[16], hn[16];
#pragma unroll
    for (int e = 0; e < 16; ++e) {
        cn[e] = (cm[e] - mu) * rs * pg[e] + pb[e];
        hn[e] = og[e] * tanh_f(cn[e]);
    }

    float* oh = out_h + (size_t)grow * HDIM;
    float* oc = out_c + (size_t)grow * HDIM;
#pragma unroll
    for (int j = 0; j < 2; ++j) {
        *(float4*)(oh + j * 512 + cbase) =
            make_float4(hn[j*8+0], hn[j*8+1], hn[j*8+2], hn[j*8+3]);
        *(float4*)(oh + j * 512 + cbase + 4) =
            make_float4(hn[j*8+4], hn[j*8+5], hn[j*8+6], hn[j*8+7]);
        *(float4*)(oc + j * 512 + cbase) =
            make_float4(cn[j*8+0], cn[j*8+1], cn[j*8+2], cn[j*8+3]);
        *(float4*)(oc + j * 512 + cbase + 4) =
            make_float4(cn[j*8+4], cn[j*8+5], cn[j*8+6], cn[j*8+7]);
    }
}

extern "C" void kernel_launch(void* const* d_in, const int* in_sizes, int n_in,
                              void* d_out, int out_size, void* d_ws, size_t ws_size,
                              hipStream_t stream)
{
    const float* input  = (const float*)d_in[0];
    const float* h_prev = (const float*)d_in[1];
    const float* c_prev = (const float*)d_in[2];
    const float* w_i    = (const float*)d_in[3];
    const float* w_h    = (const float*)d_in[4];
    const float* lng[10];
    for (int i = 0; i < 10; ++i) lng[i] = (const float*)d_in[5 + i];

    // Workspace: Xb bf16 [8192,2048] | Wb bf16 [4096,2048] | G bf16 [chunk,4096]
    unsigned short* Xb = (unsigned short*)d_ws;
    size_t xb_bytes = (size_t)BATCH * KDIM * 2;
    unsigned short* Wb = (unsigned short*)((char*)d_ws + xb_bytes);
    size_t wb_bytes = (size_t)NDIM * KDIM * 2;
    unsigned short* G = (unsigned short*)((char*)d_ws + xb_bytes + wb_bytes);

    size_t g_avail = (ws_size > xb_bytes + wb_bytes) ? (ws_size - xb_bytes - wb_bytes) : 0;
    long max_rows = (long)(g_avail / ((size_t)NDIM * sizeof(unsigned short)));
    int chunk = (max_rows >= BATCH) ? BATCH : (int)((max_rows / BM) * BM);
    if (chunk <= 0) chunk = BM;   // last-resort assumption

    convert_kernel<<<(NDIM * 512 + BATCH * 512) / 256, 256, 0, stream>>>(
        w_i, w_h, input, h_prev, Wb, Xb);

    float* out_h = (float*)d_out;
    float* out_c = out_h + (size_t)BATCH * HDIM;

    for (int rb = 0; rb < BATCH; rb += chunk) {
        int rows = (BATCH - rb < chunk) ? (BATCH - rb) : chunk;
        gemm_bt_kernel<<<(rows / BM) * (NDIM / BN), 512, 0, stream>>>(
            Xb + (size_t)rb * KDIM, Wb, G, rows);
        lstm_ew_kernel<<<rows / 4, 256, 0, stream>>>(
            G, c_prev, lng[0], lng[1], lng[2], lng[3], lng[4],
            lng[5], lng[6], lng[7], lng[8], lng[9], out_h, out_c, rb);
    }
}